// Round 3
// baseline (1099.214 us; speedup 1.0000x reference)
//
#include <hip/hip_runtime.h>

#define N_NODES 50000
#define N_EDGES 800000
#define BATCH 8
#define CH 64
#define BC (BATCH * CH)                  // 512 elems per node row (node-major layout)
#define WSZ (CH * CH)
#define NROWS (BATCH * N_NODES)          // 400000 GEMM rows
#define TELEMS ((size_t)NROWS * CH)      // 25.6M elems per t-buffer

typedef unsigned short u16;
typedef short bf16x8 __attribute__((ext_vector_type(8)));
typedef float f32x4 __attribute__((ext_vector_type(4)));
typedef unsigned short u16x4 __attribute__((ext_vector_type(4)));
typedef unsigned short u16x8 __attribute__((ext_vector_type(8)));

__device__ __forceinline__ u16 f2bf(float f) {          // RNE
    unsigned x = __float_as_uint(f);
    return (u16)((x + 0x7fffu + ((x >> 16) & 1u)) >> 16);
}
__device__ __forceinline__ float b2f(u16 u) {
    return __uint_as_float(((unsigned)u) << 16);
}

// ---------------- CSR build ----------------

__global__ void hist_kernel(const int* __restrict__ dst, int* __restrict__ cursor, int E) {
    int e = blockIdx.x * blockDim.x + threadIdx.x;
    if (e < E) atomicAdd(&cursor[dst[e]], 1);
}

__global__ void scan_kernel(int* cursor, int* __restrict__ row_ptr, int n) {
    const int T = 1024;
    int tid = threadIdx.x;
    int per = (n + T - 1) / T;
    int s = tid * per;
    int e = s + per; if (e > n) e = n;
    int sum = 0;
    for (int i = s; i < e; ++i) sum += cursor[i];
    __shared__ int lds[1024];
    lds[tid] = sum;
    __syncthreads();
    for (int off = 1; off < 1024; off <<= 1) {
        int t = (tid >= off) ? lds[tid - off] : 0;
        __syncthreads();
        lds[tid] += t;
        __syncthreads();
    }
    int run = lds[tid] - sum;
    for (int i = s; i < e; ++i) {
        int v = cursor[i];
        row_ptr[i] = run;
        cursor[i]  = run;
        run += v;
    }
    if (tid == T - 1) row_ptr[n] = run;
}

__global__ void scatter_kernel(const int* __restrict__ dst, const int* __restrict__ src,
                               const float* __restrict__ w, int* cursor,
                               int2* __restrict__ edges, int E) {
    int e = blockIdx.x * blockDim.x + threadIdx.x;
    if (e >= E) return;
    int d = dst[e];
    int p = atomicAdd(&cursor[d], 1);
    edges[p] = make_int2(src[e], __float_as_int(w[e]));
}

// ---------------- fp32 [B,N,C] -> bf16 [N,B,C] transpose-cast ----------------
__global__ __launch_bounds__(256) void cast_x(const float* __restrict__ x, u16* __restrict__ xb) {
    size_t i = (size_t)blockIdx.x * 256 + threadIdx.x;   // over B*N*16 groups of 4ch
    f32x4 v = __builtin_nontemporal_load((const f32x4*)(x + i * 4));
    int c4 = (int)(i & 15);
    size_t bn = i >> 4;                                  // b*N + n
    int b = (int)(bn / N_NODES);
    int n = (int)(bn - (size_t)b * N_NODES);
    u16x4 o;
    o.x = f2bf(v.x); o.y = f2bf(v.y); o.z = f2bf(v.z); o.w = f2bf(v.w);
    *(u16x4*)(xb + ((size_t)n * BATCH + b) * CH + c4 * 4) = o;   // cached: gather source
}

// ---------------- pack W into MFMA B-fragment layout ----------------
// frag id = (k*2 + cct)*4 + ct ; lane holds B[k=quad*8+j][col=ct*16+(lane&15)]
__global__ __launch_bounds__(256) void pack_w(const float* __restrict__ W, u16* __restrict__ wpack) {
    int id = blockIdx.x * 256 + threadIdx.x;     // 48 frags * 64 lanes = 3072
    if (id >= 48 * 64) return;
    int lane = id & 63, frag = id >> 6;
    int ct = frag & 3, cct = (frag >> 2) & 1, k = frag >> 3;
    int m = lane & 15, quad = lane >> 4;
    int c = ct * 16 + m;
#pragma unroll
    for (int j = 0; j < 8; ++j) {
        int cc = cct * 32 + quad * 8 + j;
        wpack[(size_t)id * 8 + j] = f2bf(W[k * WSZ + cc * CH + c]);
    }
}

// ---------------- SPMM step: wave-per-node (grid-strided), node-major layout ----
// One wave owns one node at a time: per edge, ONE dwordx4 load fetches the full
// 1KB src row (lane l -> batch l>>3, channels (l&7)*8 .. +8).
// Edge loop unrolled 4-wide for MLP; padded slots use weight=0 (fmaf(0,x,acc)
// is exact), so per-(b,c) accumulation order matches the reference CSR order.
template <bool HAS_PREV>
__global__ __launch_bounds__(256) void spmm_kernel(
        const u16* __restrict__ tcur,
        const u16* __restrict__ tprev,
        u16* __restrict__ tnext,
        const int* __restrict__ row_ptr,
        const int2* __restrict__ edges) {
    const int nwaves = gridDim.x * 4;
    const int wid = blockIdx.x * 4 + (threadIdx.x >> 6);
    const int lane = threadIdx.x & 63;
    const size_t lo = (size_t)lane * 8;

    for (int node = wid; node < N_NODES; node += nwaves) {
        float acc[8];
#pragma unroll
        for (int q = 0; q < 8; ++q) acc[q] = 0.f;

        const int beg = row_ptr[node], end = row_ptr[node + 1];
        for (int e0 = beg; e0 < end; e0 += 64) {
            int m = end - e0; if (m > 64) m = 64;
            int2 ev = edges[e0 + (lane < m ? lane : 0)];
            for (int j = 0; j < m; j += 4) {
                int   s0 = __shfl(ev.x, j);
                float w0 = __int_as_float(__shfl(ev.y, j));
                int   j1 = (j + 1 < m) ? j + 1 : j;
                int   s1 = __shfl(ev.x, j1);
                float w1 = (j + 1 < m) ? __int_as_float(__shfl(ev.y, j1)) : 0.f;
                int   j2 = (j + 2 < m) ? j + 2 : j;
                int   s2 = __shfl(ev.x, j2);
                float w2 = (j + 2 < m) ? __int_as_float(__shfl(ev.y, j2)) : 0.f;
                int   j3 = (j + 3 < m) ? j + 3 : j;
                int   s3 = __shfl(ev.x, j3);
                float w3 = (j + 3 < m) ? __int_as_float(__shfl(ev.y, j3)) : 0.f;
                u16x8 v0 = *(const u16x8*)(tcur + (size_t)s0 * BC + lo);
                u16x8 v1 = *(const u16x8*)(tcur + (size_t)s1 * BC + lo);
                u16x8 v2 = *(const u16x8*)(tcur + (size_t)s2 * BC + lo);
                u16x8 v3 = *(const u16x8*)(tcur + (size_t)s3 * BC + lo);
#pragma unroll
                for (int q = 0; q < 8; ++q) acc[q] = fmaf(w0, b2f(v0[q]), acc[q]);
#pragma unroll
                for (int q = 0; q < 8; ++q) acc[q] = fmaf(w1, b2f(v1[q]), acc[q]);
#pragma unroll
                for (int q = 0; q < 8; ++q) acc[q] = fmaf(w2, b2f(v2[q]), acc[q]);
#pragma unroll
                for (int q = 0; q < 8; ++q) acc[q] = fmaf(w3, b2f(v3[q]), acc[q]);
            }
        }

        const size_t idx = (size_t)node * BC + lo;
        u16x8 o;
        if (HAS_PREV) {
            u16x8 pv = *(const u16x8*)(tprev + idx);
#pragma unroll
            for (int q = 0; q < 8; ++q) o[q] = f2bf(2.f * acc[q] - b2f(pv[q]));
        } else {
#pragma unroll
            for (int q = 0; q < 8; ++q) o[q] = f2bf(acc[q]);
        }
        *(u16x8*)(tnext + idx) = o;   // cached: next step's gather source
    }
}

// ---------------- final GEMM: out = bias + sum_k t_k @ W_k (MFMA bf16) ----------------
// wave = one 16-row tile (rows are (n,b) pairs: r = n*8 + b), all 64 output cols.
// C-store remaps to out[b][n][c]. accum=1: out += ..., accum=0: out = bias + ...
__global__ __launch_bounds__(256) void out_gemm(
        const u16* __restrict__ tbase, size_t tstride,
        const u16* __restrict__ wpack,      // already offset by k0*WSZ
        const float* __restrict__ bias,
        float* __restrict__ out, int nk, int accum) {
    const int wave = threadIdx.x >> 6, lane = threadIdx.x & 63;
    const int tile = blockIdx.x * 4 + wave;          // 25000 tiles
    const int row0 = tile * 16;
    const int m = lane & 15, quad = lane >> 4;

    f32x4 acc[4];
#pragma unroll
    for (int ct = 0; ct < 4; ++ct) acc[ct] = (f32x4){0.f, 0.f, 0.f, 0.f};

    for (int k = 0; k < nk; ++k) {
        const u16* t = tbase + (size_t)k * tstride;
#pragma unroll
        for (int cct = 0; cct < 2; ++cct) {
            bf16x8 A = *(const bf16x8*)(t + (size_t)(row0 + m) * CH + cct * 32 + quad * 8);
#pragma unroll
            for (int ct = 0; ct < 4; ++ct) {
                bf16x8 B = *(const bf16x8*)(wpack + (size_t)(((k * 2 + cct) * 4 + ct) * 64 + lane) * 8);
                acc[ct] = __builtin_amdgcn_mfma_f32_16x16x32_bf16(A, B, acc[ct], 0, 0, 0);
            }
        }
    }

#pragma unroll
    for (int ct = 0; ct < 4; ++ct) {
        const int c = ct * 16 + m;
        const float bv = bias[c];
#pragma unroll
        for (int r = 0; r < 4; ++r) {
            int row = row0 + quad * 4 + r;            // = n*8 + b
            float* op = out + ((size_t)(row & 7) * N_NODES + (row >> 3)) * CH + c;
            float v = acc[ct][r];
            if (accum) v += __builtin_nontemporal_load(op);
            else       v += bv;
            __builtin_nontemporal_store(v, op);
        }
    }
}

extern "C" void kernel_launch(void* const* d_in, const int* in_sizes, int n_in,
                              void* d_out, int out_size, void* d_ws, size_t ws_size,
                              hipStream_t stream) {
    const float* x    = (const float*)d_in[0];   // [B,N,C]
    const int*   ei   = (const int*)d_in[1];     // [2,E]: row0=dst, row1=src
    const float* ew   = (const float*)d_in[2];   // [E]
    const float* W    = (const float*)d_in[3];   // [K,64,64]
    const float* bias = (const float*)d_in[4];   // [64]
    float* out = (float*)d_out;

    const int* dst = ei;
    const int* src = ei + N_EDGES;

    const size_t SB = TELEMS * sizeof(u16);      // 51.2 MB per t-buffer
    const size_t EXTRA = 2 * 200192 + (size_t)N_EDGES * sizeof(int2) + 49664;
    const size_t NEED_PRIMARY = 6 * SB + EXTRA;  // ~314.3 MB
    const bool primary = (ws_size >= NEED_PRIMARY);
    const int nbuf = primary ? 6 : 3;

    char* ws = (char*)d_ws;
    size_t off = 0;
    u16* tbase = (u16*)(ws + off); off += (size_t)nbuf * SB;   // t0(=x bf16), t1..
    int* row_ptr = (int*)(ws + off); off += 200192;
    int* cursor  = (int*)(ws + off); off += 200192;
    int2* edges  = (int2*)(ws + off); off += (size_t)N_EDGES * sizeof(int2);
    u16* wpack   = (u16*)(ws + off); off += 49664;
    (void)off; (void)n_in; (void)in_sizes; (void)out_size;

    // ---- CSR build + precompute ----
    (void)hipMemsetAsync(cursor, 0, (size_t)N_NODES * sizeof(int), stream);
    hist_kernel<<<(N_EDGES + 255) / 256, 256, 0, stream>>>(dst, cursor, N_EDGES);
    scan_kernel<<<1, 1024, 0, stream>>>(cursor, row_ptr, N_NODES);
    scatter_kernel<<<(N_EDGES + 255) / 256, 256, 0, stream>>>(dst, src, ew, cursor,
                                                              edges, N_EDGES);
    cast_x<<<(int)(TELEMS / 4 / 256), 256, 0, stream>>>(x, tbase);
    pack_w<<<12, 256, 0, stream>>>(W, wpack);

    const int SPMM_GRID = 2048;                  // grid-strided: 8192 waves over 50000 nodes
    u16* t0 = tbase;
    if (primary) {
        u16* t1 = tbase + 1 * TELEMS;
        u16* t2 = tbase + 2 * TELEMS;
        u16* t3 = tbase + 3 * TELEMS;
        u16* t4 = tbase + 4 * TELEMS;
        u16* t5 = tbase + 5 * TELEMS;
        spmm_kernel<false><<<SPMM_GRID, 256, 0, stream>>>(t0, nullptr, t1, row_ptr, edges);
        spmm_kernel<true ><<<SPMM_GRID, 256, 0, stream>>>(t1, t0, t2, row_ptr, edges);
        spmm_kernel<true ><<<SPMM_GRID, 256, 0, stream>>>(t2, t1, t3, row_ptr, edges);
        spmm_kernel<true ><<<SPMM_GRID, 256, 0, stream>>>(t3, t2, t4, row_ptr, edges);
        spmm_kernel<true ><<<SPMM_GRID, 256, 0, stream>>>(t4, t3, t5, row_ptr, edges);
        out_gemm<<<NROWS / 16 / 4, 256, 0, stream>>>(tbase, TELEMS, wpack, bias, out, 6, 0);
    } else {
        // fallback: 3 rotating buffers + incremental GEMM accumulation
        u16* t1 = tbase + 1 * TELEMS;
        u16* t2 = tbase + 2 * TELEMS;
        const int GG = NROWS / 16 / 4;
        spmm_kernel<false><<<SPMM_GRID, 256, 0, stream>>>(t0, nullptr, t1, row_ptr, edges);
        out_gemm<<<GG, 256, 0, stream>>>(t0, TELEMS, wpack, bias, out, 2, 0);          // bias + T0@W0 + T1@W1
        spmm_kernel<true ><<<SPMM_GRID, 256, 0, stream>>>(t1, t0, t2, row_ptr, edges); // T2 -> t2
        out_gemm<<<GG, 256, 0, stream>>>(t2, TELEMS, wpack + 2 * WSZ, bias, out, 1, 1);
        spmm_kernel<true ><<<SPMM_GRID, 256, 0, stream>>>(t2, t1, t0, row_ptr, edges); // T3 -> t0
        out_gemm<<<GG, 256, 0, stream>>>(t0, TELEMS, wpack + 3 * WSZ, bias, out, 1, 1);
        spmm_kernel<true ><<<SPMM_GRID, 256, 0, stream>>>(t0, t2, t1, row_ptr, edges); // T4 -> t1
        out_gemm<<<GG, 256, 0, stream>>>(t1, TELEMS, wpack + 4 * WSZ, bias, out, 1, 1);
        spmm_kernel<true ><<<SPMM_GRID, 256, 0, stream>>>(t1, t0, t2, row_ptr, edges); // T5 -> t2
        out_gemm<<<GG, 256, 0, stream>>>(t2, TELEMS, wpack + 5 * WSZ, bias, out, 1, 1);
    }
}

// Round 5
// 1068.318 us; speedup vs baseline: 1.0289x; 1.0289x over previous
//
#include <hip/hip_runtime.h>

#define N_NODES 50000
#define N_EDGES 800000
#define BATCH 8
#define CH 64
#define BC (BATCH * CH)                  // 512 elems per node row (node-major layout)
#define WSZ (CH * CH)
#define NROWS (BATCH * N_NODES)          // 400000 GEMM rows
#define TELEMS ((size_t)NROWS * CH)      // 25.6M elems per t-buffer
#define HIST_BLOCKS ((N_EDGES + 255) / 256)      // 3125
#define CAST_BLOCKS ((int)(TELEMS / 4 / 256))    // 25000
#define PACK_BLOCKS 12

typedef unsigned short u16;
typedef short bf16x8 __attribute__((ext_vector_type(8)));
typedef float f32x4 __attribute__((ext_vector_type(4)));
typedef unsigned short u16x4 __attribute__((ext_vector_type(4)));
typedef unsigned short u16x8 __attribute__((ext_vector_type(8)));

__device__ __forceinline__ u16 f2bf(float f) {          // RNE
    unsigned x = __float_as_uint(f);
    return (u16)((x + 0x7fffu + ((x >> 16) & 1u)) >> 16);
}
__device__ __forceinline__ float b2f(u16 u) {
    return __uint_as_float(((unsigned)u) << 16);
}

// ---------------- CSR build + input prep ----------------

// fused: blocks [0, HIST_BLOCKS) do the dst histogram; the rest transpose-cast
// x fp32 [B,N,C] -> bf16 [N,B,C]. Independent work, overlapped in one launch.
__global__ __launch_bounds__(256) void hist_cast_kernel(
        const int* __restrict__ dst, int* __restrict__ cursor,
        const float* __restrict__ x, u16* __restrict__ xb) {
    int bid = blockIdx.x;
    if (bid < HIST_BLOCKS) {
        int e = bid * 256 + threadIdx.x;
        if (e < N_EDGES) atomicAdd(&cursor[dst[e]], 1);
        return;
    }
    size_t i = (size_t)(bid - HIST_BLOCKS) * 256 + threadIdx.x;   // B*N*16 groups of 4ch
    f32x4 v = __builtin_nontemporal_load((const f32x4*)(x + i * 4));
    int c4 = (int)(i & 15);
    size_t bn = i >> 4;                                  // b*N + n
    int b = (int)(bn / N_NODES);
    int n = (int)(bn - (size_t)b * N_NODES);
    u16x4 o;
    o.x = f2bf(v.x); o.y = f2bf(v.y); o.z = f2bf(v.z); o.w = f2bf(v.w);
    *(u16x4*)(xb + ((size_t)n * BATCH + b) * CH + c4 * 4) = o;   // cached: gather source
}

__global__ void scan_kernel(int* cursor, int* __restrict__ row_ptr, int n) {
    const int T = 1024;
    int tid = threadIdx.x;
    int per = (n + T - 1) / T;
    int s = tid * per;
    int e = s + per; if (e > n) e = n;
    int sum = 0;
    for (int i = s; i < e; ++i) sum += cursor[i];
    __shared__ int lds[1024];
    lds[tid] = sum;
    __syncthreads();
    for (int off = 1; off < 1024; off <<= 1) {
        int t = (tid >= off) ? lds[tid - off] : 0;
        __syncthreads();
        lds[tid] += t;
        __syncthreads();
    }
    int run = lds[tid] - sum;
    for (int i = s; i < e; ++i) {
        int v = cursor[i];
        row_ptr[i] = run;
        cursor[i]  = run;
        run += v;
    }
    if (tid == T - 1) row_ptr[n] = run;
}

// fused: blocks [0, HIST_BLOCKS) scatter edges into CSR slots; the rest pack W
// into the MFMA B-fragment layout (frag id = (k*2+cct)*4+ct; lane holds
// B[k=quad*8+j][col=ct*16+(lane&15)]).
__global__ __launch_bounds__(256) void scatter_pack_kernel(
        const int* __restrict__ dst, const int* __restrict__ src,
        const float* __restrict__ w, int* cursor, int2* __restrict__ edges,
        const float* __restrict__ W, u16* __restrict__ wpack) {
    int bid = blockIdx.x;
    if (bid < HIST_BLOCKS) {
        int e = bid * 256 + threadIdx.x;
        if (e >= N_EDGES) return;
        int d = dst[e];
        int p = atomicAdd(&cursor[d], 1);
        edges[p] = make_int2(src[e], __float_as_int(w[e]));
        return;
    }
    int id = (bid - HIST_BLOCKS) * 256 + threadIdx.x;   // 48 frags * 64 lanes = 3072
    if (id >= 48 * 64) return;
    int lane = id & 63, frag = id >> 6;
    int ct = frag & 3, cct = (frag >> 2) & 1, k = frag >> 3;
    int m = lane & 15, quad = lane >> 4;
    int c = ct * 16 + m;
#pragma unroll
    for (int j = 0; j < 8; ++j) {
        int cc = cct * 32 + quad * 8 + j;
        wpack[(size_t)id * 8 + j] = f2bf(W[k * WSZ + cc * CH + c]);
    }
}

// ---------------- SPMM step: wave-per-node, node-major layout ----------------
// One wave owns one node: per edge, ONE dwordx4 load fetches the full 1KB src
// row (lane l -> batch l>>3, channels (l&7)*8 .. +8). Edge loop is 4-wide for
// MLP with a ZERO-WASTE wave-uniform tail (no padded loads: every issued load
// is a real edge). Per-(b,c) accumulation order matches the CSR edge order.
template <bool HAS_PREV>
__global__ __launch_bounds__(256) void spmm_kernel(
        const u16* __restrict__ tcur,
        const u16* __restrict__ tprev,
        u16* __restrict__ tnext,
        const int* __restrict__ row_ptr,
        const int2* __restrict__ edges) {
    const int node = blockIdx.x * 4 + (threadIdx.x >> 6);
    const int lane = threadIdx.x & 63;
    const size_t lo = (size_t)lane * 8;

    float acc[8];
#pragma unroll
    for (int q = 0; q < 8; ++q) acc[q] = 0.f;

    const int beg = row_ptr[node], end = row_ptr[node + 1];
    for (int e0 = beg; e0 < end; e0 += 64) {
        int m = end - e0; if (m > 64) m = 64;
        int2 ev = edges[e0 + (lane < m ? lane : 0)];
        int j = 0;
        for (; j + 4 <= m; j += 4) {                 // no predication, no waste
            int   s0 = __shfl(ev.x, j);
            int   s1 = __shfl(ev.x, j + 1);
            int   s2 = __shfl(ev.x, j + 2);
            int   s3 = __shfl(ev.x, j + 3);
            float w0 = __int_as_float(__shfl(ev.y, j));
            float w1 = __int_as_float(__shfl(ev.y, j + 1));
            float w2 = __int_as_float(__shfl(ev.y, j + 2));
            float w3 = __int_as_float(__shfl(ev.y, j + 3));
            u16x8 v0 = *(const u16x8*)(tcur + (size_t)s0 * BC + lo);
            u16x8 v1 = *(const u16x8*)(tcur + (size_t)s1 * BC + lo);
            u16x8 v2 = *(const u16x8*)(tcur + (size_t)s2 * BC + lo);
            u16x8 v3 = *(const u16x8*)(tcur + (size_t)s3 * BC + lo);
#pragma unroll
            for (int q = 0; q < 8; ++q) acc[q] = fmaf(w0, b2f(v0[q]), acc[q]);
#pragma unroll
            for (int q = 0; q < 8; ++q) acc[q] = fmaf(w1, b2f(v1[q]), acc[q]);
#pragma unroll
            for (int q = 0; q < 8; ++q) acc[q] = fmaf(w2, b2f(v2[q]), acc[q]);
#pragma unroll
            for (int q = 0; q < 8; ++q) acc[q] = fmaf(w3, b2f(v3[q]), acc[q]);
        }
        for (; j < m; ++j) {                         // wave-uniform tail, 0..3 edges
            int   s = __shfl(ev.x, j);
            float w = __int_as_float(__shfl(ev.y, j));
            u16x8 v = *(const u16x8*)(tcur + (size_t)s * BC + lo);
#pragma unroll
            for (int q = 0; q < 8; ++q) acc[q] = fmaf(w, b2f(v[q]), acc[q]);
        }
    }

    const size_t idx = (size_t)node * BC + lo;
    u16x8 o;
    if (HAS_PREV) {
        u16x8 pv = *(const u16x8*)(tprev + idx);
#pragma unroll
        for (int q = 0; q < 8; ++q) o[q] = f2bf(2.f * acc[q] - b2f(pv[q]));
    } else {
#pragma unroll
        for (int q = 0; q < 8; ++q) o[q] = f2bf(acc[q]);
    }
    *(u16x8*)(tnext + idx) = o;   // cached: next step's gather source
}

// ---------------- final GEMM: out = bias + sum_k t_k @ W_k (MFMA bf16) ----------------
// wave = one 16-row tile (rows are (n,b) pairs: r = n*8 + b), all 64 output cols.
// C-store remaps to out[b][n][c]. accum=1: out += ..., accum=0: out = bias + ...
__global__ __launch_bounds__(256) void out_gemm(
        const u16* __restrict__ tbase, size_t tstride,
        const u16* __restrict__ wpack,      // already offset by k0*WSZ
        const float* __restrict__ bias,
        float* __restrict__ out, int nk, int accum) {
    const int wave = threadIdx.x >> 6, lane = threadIdx.x & 63;
    const int tile = blockIdx.x * 4 + wave;          // 25000 tiles
    const int row0 = tile * 16;
    const int m = lane & 15, quad = lane >> 4;

    f32x4 acc[4];
#pragma unroll
    for (int ct = 0; ct < 4; ++ct) acc[ct] = (f32x4){0.f, 0.f, 0.f, 0.f};

    for (int k = 0; k < nk; ++k) {
        const u16* t = tbase + (size_t)k * tstride;
#pragma unroll
        for (int cct = 0; cct < 2; ++cct) {
            bf16x8 A = *(const bf16x8*)(t + (size_t)(row0 + m) * CH + cct * 32 + quad * 8);
#pragma unroll
            for (int ct = 0; ct < 4; ++ct) {
                bf16x8 B = *(const bf16x8*)(wpack + (size_t)(((k * 2 + cct) * 4 + ct) * 64 + lane) * 8);
                acc[ct] = __builtin_amdgcn_mfma_f32_16x16x32_bf16(A, B, acc[ct], 0, 0, 0);
            }
        }
    }

#pragma unroll
    for (int ct = 0; ct < 4; ++ct) {
        const int c = ct * 16 + m;
        const float bv = bias[c];
#pragma unroll
        for (int r = 0; r < 4; ++r) {
            int row = row0 + quad * 4 + r;            // = n*8 + b
            float* op = out + ((size_t)(row & 7) * N_NODES + (row >> 3)) * CH + c;
            float v = acc[ct][r];
            if (accum) v += __builtin_nontemporal_load(op);
            else       v += bv;
            __builtin_nontemporal_store(v, op);
        }
    }
}

extern "C" void kernel_launch(void* const* d_in, const int* in_sizes, int n_in,
                              void* d_out, int out_size, void* d_ws, size_t ws_size,
                              hipStream_t stream) {
    const float* x    = (const float*)d_in[0];   // [B,N,C]
    const int*   ei   = (const int*)d_in[1];     // [2,E]: row0=dst, row1=src
    const float* ew   = (const float*)d_in[2];   // [E]
    const float* W    = (const float*)d_in[3];   // [K,64,64]
    const float* bias = (const float*)d_in[4];   // [64]
    float* out = (float*)d_out;

    const int* dst = ei;
    const int* src = ei + N_EDGES;

    const size_t SB = TELEMS * sizeof(u16);      // 51.2 MB per t-buffer
    const size_t EXTRA = 2 * 200192 + (size_t)N_EDGES * sizeof(int2) + 49664;
    const size_t NEED_PRIMARY = 6 * SB + EXTRA;  // ~314.3 MB
    const bool primary = (ws_size >= NEED_PRIMARY);
    const int nbuf = primary ? 6 : 3;

    char* ws = (char*)d_ws;
    size_t off = 0;
    u16* tbase = (u16*)(ws + off); off += (size_t)nbuf * SB;   // t0(=x bf16), t1..
    int* row_ptr = (int*)(ws + off); off += 200192;
    int* cursor  = (int*)(ws + off); off += 200192;
    int2* edges  = (int2*)(ws + off); off += (size_t)N_EDGES * sizeof(int2);
    u16* wpack   = (u16*)(ws + off); off += 49664;
    (void)off; (void)n_in; (void)in_sizes; (void)out_size;

    // ---- CSR build + precompute (fused launches) ----
    (void)hipMemsetAsync(cursor, 0, (size_t)N_NODES * sizeof(int), stream);
    hist_cast_kernel<<<HIST_BLOCKS + CAST_BLOCKS, 256, 0, stream>>>(dst, cursor, x, tbase);
    scan_kernel<<<1, 1024, 0, stream>>>(cursor, row_ptr, N_NODES);
    scatter_pack_kernel<<<HIST_BLOCKS + PACK_BLOCKS, 256, 0, stream>>>(dst, src, ew, cursor,
                                                                       edges, W, wpack);

    const int SPMM_GRID = N_NODES / 4;           // 12500 blocks, 1 node per wave
    u16* t0 = tbase;
    if (primary) {
        u16* t1 = tbase + 1 * TELEMS;
        u16* t2 = tbase + 2 * TELEMS;
        u16* t3 = tbase + 3 * TELEMS;
        u16* t4 = tbase + 4 * TELEMS;
        u16* t5 = tbase + 5 * TELEMS;
        spmm_kernel<false><<<SPMM_GRID, 256, 0, stream>>>(t0, nullptr, t1, row_ptr, edges);
        spmm_kernel<true ><<<SPMM_GRID, 256, 0, stream>>>(t1, t0, t2, row_ptr, edges);
        spmm_kernel<true ><<<SPMM_GRID, 256, 0, stream>>>(t2, t1, t3, row_ptr, edges);
        spmm_kernel<true ><<<SPMM_GRID, 256, 0, stream>>>(t3, t2, t4, row_ptr, edges);
        spmm_kernel<true ><<<SPMM_GRID, 256, 0, stream>>>(t4, t3, t5, row_ptr, edges);
        out_gemm<<<NROWS / 16 / 4, 256, 0, stream>>>(tbase, TELEMS, wpack, bias, out, 6, 0);
    } else {
        // fallback: 3 rotating buffers + incremental GEMM accumulation
        u16* t1 = tbase + 1 * TELEMS;
        u16* t2 = tbase + 2 * TELEMS;
        const int GG = NROWS / 16 / 4;
        spmm_kernel<false><<<SPMM_GRID, 256, 0, stream>>>(t0, nullptr, t1, row_ptr, edges);
        out_gemm<<<GG, 256, 0, stream>>>(t0, TELEMS, wpack, bias, out, 2, 0);          // bias + T0@W0 + T1@W1
        spmm_kernel<true ><<<SPMM_GRID, 256, 0, stream>>>(t1, t0, t2, row_ptr, edges); // T2 -> t2
        out_gemm<<<GG, 256, 0, stream>>>(t2, TELEMS, wpack + 2 * WSZ, bias, out, 1, 1);
        spmm_kernel<true ><<<SPMM_GRID, 256, 0, stream>>>(t2, t1, t0, row_ptr, edges); // T3 -> t0
        out_gemm<<<GG, 256, 0, stream>>>(t0, TELEMS, wpack + 3 * WSZ, bias, out, 1, 1);
        spmm_kernel<true ><<<SPMM_GRID, 256, 0, stream>>>(t0, t2, t1, row_ptr, edges); // T4 -> t1
        out_gemm<<<GG, 256, 0, stream>>>(t1, TELEMS, wpack + 4 * WSZ, bias, out, 1, 1);
        spmm_kernel<true ><<<SPMM_GRID, 256, 0, stream>>>(t1, t0, t2, row_ptr, edges); // T5 -> t2
        out_gemm<<<GG, 256, 0, stream>>>(t2, TELEMS, wpack + 5 * WSZ, bias, out, 1, 1);
    }
}

// Round 6
// 1019.176 us; speedup vs baseline: 1.0785x; 1.0482x over previous
//
#include <hip/hip_runtime.h>

#define N_NODES 50000
#define N_EDGES 800000
#define BATCH 8
#define CH 64
#define BC (BATCH * CH)                  // 512 elems per node row (node-major layout)
#define WSZ (CH * CH)
#define NROWS (BATCH * N_NODES)          // 400000 GEMM rows
#define TELEMS ((size_t)NROWS * CH)      // 25.6M elems per t-buffer
#define HIST_BLOCKS ((N_EDGES + 255) / 256)      // 3125
#define CAST_BLOCKS ((int)(TELEMS / 4 / 256))    // 25000
#define PACK_BLOCKS 12

typedef unsigned short u16;
typedef short bf16x8 __attribute__((ext_vector_type(8)));
typedef float f32x4 __attribute__((ext_vector_type(4)));
typedef unsigned short u16x4 __attribute__((ext_vector_type(4)));
typedef unsigned short u16x8 __attribute__((ext_vector_type(8)));

__device__ __forceinline__ u16 f2bf(float f) {          // RNE
    unsigned x = __float_as_uint(f);
    return (u16)((x + 0x7fffu + ((x >> 16) & 1u)) >> 16);
}
__device__ __forceinline__ float b2f(u16 u) {
    return __uint_as_float(((unsigned)u) << 16);
}

// ---------------- CSR build + input prep ----------------

// fused: blocks [0, HIST_BLOCKS) do the dst histogram; the rest transpose-cast
// x fp32 [B,N,C] -> bf16 [N,B,C]. Independent work, overlapped in one launch.
__global__ __launch_bounds__(256) void hist_cast_kernel(
        const int* __restrict__ dst, int* __restrict__ cursor,
        const float* __restrict__ x, u16* __restrict__ xb) {
    int bid = blockIdx.x;
    if (bid < HIST_BLOCKS) {
        int e = bid * 256 + threadIdx.x;
        if (e < N_EDGES) atomicAdd(&cursor[dst[e]], 1);
        return;
    }
    size_t i = (size_t)(bid - HIST_BLOCKS) * 256 + threadIdx.x;   // B*N*16 groups of 4ch
    f32x4 v = __builtin_nontemporal_load((const f32x4*)(x + i * 4));
    int c4 = (int)(i & 15);
    size_t bn = i >> 4;                                  // b*N + n
    int b = (int)(bn / N_NODES);
    int n = (int)(bn - (size_t)b * N_NODES);
    u16x4 o;
    o.x = f2bf(v.x); o.y = f2bf(v.y); o.z = f2bf(v.z); o.w = f2bf(v.w);
    *(u16x4*)(xb + ((size_t)n * BATCH + b) * CH + c4 * 4) = o;   // cached: gather source
}

__global__ void scan_kernel(int* cursor, int* __restrict__ row_ptr, int n) {
    const int T = 1024;
    int tid = threadIdx.x;
    int per = (n + T - 1) / T;
    int s = tid * per;
    int e = s + per; if (e > n) e = n;
    int sum = 0;
    for (int i = s; i < e; ++i) sum += cursor[i];
    __shared__ int lds[1024];
    lds[tid] = sum;
    __syncthreads();
    for (int off = 1; off < 1024; off <<= 1) {
        int t = (tid >= off) ? lds[tid - off] : 0;
        __syncthreads();
        lds[tid] += t;
        __syncthreads();
    }
    int run = lds[tid] - sum;
    for (int i = s; i < e; ++i) {
        int v = cursor[i];
        row_ptr[i] = run;
        cursor[i]  = run;
        run += v;
    }
    if (tid == T - 1) row_ptr[n] = run;
}

// fused: blocks [0, HIST_BLOCKS) scatter edges into CSR slots; the rest pack W
// into the MFMA B-fragment layout (frag id = (k*2+cct)*4+ct; lane holds
// B[k=quad*8+j][col=ct*16+(lane&15)]).
__global__ __launch_bounds__(256) void scatter_pack_kernel(
        const int* __restrict__ dst, const int* __restrict__ src,
        const float* __restrict__ w, int* cursor, int2* __restrict__ edges,
        const float* __restrict__ W, u16* __restrict__ wpack) {
    int bid = blockIdx.x;
    if (bid < HIST_BLOCKS) {
        int e = bid * 256 + threadIdx.x;
        if (e >= N_EDGES) return;
        int d = dst[e];
        int p = atomicAdd(&cursor[d], 1);
        edges[p] = make_int2(src[e], __float_as_int(w[e]));
        return;
    }
    int id = (bid - HIST_BLOCKS) * 256 + threadIdx.x;   // 48 frags * 64 lanes = 3072
    if (id >= 48 * 64) return;
    int lane = id & 63, frag = id >> 6;
    int ct = frag & 3, cct = (frag >> 2) & 1, k = frag >> 3;
    int m = lane & 15, quad = lane >> 4;
    int c = ct * 16 + m;
#pragma unroll
    for (int j = 0; j < 8; ++j) {
        int cc = cct * 32 + quad * 8 + j;
        wpack[(size_t)id * 8 + j] = f2bf(W[k * WSZ + cc * CH + c]);
    }
}

// ---------------- SPMM half-step: wave-per-node, batch-half, node-major ------
// The Chebyshev recursion is independent per batch, so each SPMM is split into
// two half-passes over batches [0,4) / [4,8): gather working set halves to
// 25.6 MB (locality experiment vs the 401-MB-FETCH plateau). Lane l covers
// batch half*4 + (l>>4), channels (l&15)*4..+4 (8B u16x4 load; wave = 512B
// contiguous half-row). Per-(b,c) FMA order is bit-identical to the full-row
// version: same CSR edge order, same fmaf chain.
template <bool HAS_PREV>
__global__ __launch_bounds__(256) void spmm_kernel(
        const u16* __restrict__ tcur,
        const u16* __restrict__ tprev,
        u16* __restrict__ tnext,
        const int* __restrict__ row_ptr,
        const int2* __restrict__ edges,
        int half) {
    const int node = blockIdx.x * 4 + (threadIdx.x >> 6);
    const int lane = threadIdx.x & 63;
    const size_t lo = (size_t)half * 256 + (size_t)lane * 4;

    float acc[4];
#pragma unroll
    for (int q = 0; q < 4; ++q) acc[q] = 0.f;

    const int beg = row_ptr[node], end = row_ptr[node + 1];
    for (int e0 = beg; e0 < end; e0 += 64) {
        int m = end - e0; if (m > 64) m = 64;
        int2 ev = edges[e0 + (lane < m ? lane : 0)];
        int j = 0;
        for (; j + 4 <= m; j += 4) {                 // no predication, no waste
            int   s0 = __shfl(ev.x, j);
            int   s1 = __shfl(ev.x, j + 1);
            int   s2 = __shfl(ev.x, j + 2);
            int   s3 = __shfl(ev.x, j + 3);
            float w0 = __int_as_float(__shfl(ev.y, j));
            float w1 = __int_as_float(__shfl(ev.y, j + 1));
            float w2 = __int_as_float(__shfl(ev.y, j + 2));
            float w3 = __int_as_float(__shfl(ev.y, j + 3));
            u16x4 v0 = *(const u16x4*)(tcur + (size_t)s0 * BC + lo);
            u16x4 v1 = *(const u16x4*)(tcur + (size_t)s1 * BC + lo);
            u16x4 v2 = *(const u16x4*)(tcur + (size_t)s2 * BC + lo);
            u16x4 v3 = *(const u16x4*)(tcur + (size_t)s3 * BC + lo);
#pragma unroll
            for (int q = 0; q < 4; ++q) acc[q] = fmaf(w0, b2f(v0[q]), acc[q]);
#pragma unroll
            for (int q = 0; q < 4; ++q) acc[q] = fmaf(w1, b2f(v1[q]), acc[q]);
#pragma unroll
            for (int q = 0; q < 4; ++q) acc[q] = fmaf(w2, b2f(v2[q]), acc[q]);
#pragma unroll
            for (int q = 0; q < 4; ++q) acc[q] = fmaf(w3, b2f(v3[q]), acc[q]);
        }
        for (; j < m; ++j) {                         // wave-uniform tail, 0..3 edges
            int   s = __shfl(ev.x, j);
            float w = __int_as_float(__shfl(ev.y, j));
            u16x4 v = *(const u16x4*)(tcur + (size_t)s * BC + lo);
#pragma unroll
            for (int q = 0; q < 4; ++q) acc[q] = fmaf(w, b2f(v[q]), acc[q]);
        }
    }

    const size_t idx = (size_t)node * BC + lo;
    u16x4 o;
    if (HAS_PREV) {
        u16x4 pv = *(const u16x4*)(tprev + idx);
#pragma unroll
        for (int q = 0; q < 4; ++q) o[q] = f2bf(2.f * acc[q] - b2f(pv[q]));
    } else {
#pragma unroll
        for (int q = 0; q < 4; ++q) o[q] = f2bf(acc[q]);
    }
    *(u16x4*)(tnext + idx) = o;   // cached: next half-step's gather source
}

// ---------------- final GEMM: out = bias + sum_k t_k @ W_k (MFMA bf16) ----------------
// wave = one 16-row tile (rows are (n,b) pairs: r = n*8 + b), all 64 output cols.
// C-store remaps to out[b][n][c]. accum=1: out += ..., accum=0: out = bias + ...
__global__ __launch_bounds__(256) void out_gemm(
        const u16* __restrict__ tbase, size_t tstride,
        const u16* __restrict__ wpack,      // already offset by k0*WSZ
        const float* __restrict__ bias,
        float* __restrict__ out, int nk, int accum) {
    const int wave = threadIdx.x >> 6, lane = threadIdx.x & 63;
    const int tile = blockIdx.x * 4 + wave;          // 25000 tiles
    const int row0 = tile * 16;
    const int m = lane & 15, quad = lane >> 4;

    f32x4 acc[4];
#pragma unroll
    for (int ct = 0; ct < 4; ++ct) acc[ct] = (f32x4){0.f, 0.f, 0.f, 0.f};

    for (int k = 0; k < nk; ++k) {
        const u16* t = tbase + (size_t)k * tstride;
#pragma unroll
        for (int cct = 0; cct < 2; ++cct) {
            bf16x8 A = *(const bf16x8*)(t + (size_t)(row0 + m) * CH + cct * 32 + quad * 8);
#pragma unroll
            for (int ct = 0; ct < 4; ++ct) {
                bf16x8 B = *(const bf16x8*)(wpack + (size_t)(((k * 2 + cct) * 4 + ct) * 64 + lane) * 8);
                acc[ct] = __builtin_amdgcn_mfma_f32_16x16x32_bf16(A, B, acc[ct], 0, 0, 0);
            }
        }
    }

#pragma unroll
    for (int ct = 0; ct < 4; ++ct) {
        const int c = ct * 16 + m;
        const float bv = bias[c];
#pragma unroll
        for (int r = 0; r < 4; ++r) {
            int row = row0 + quad * 4 + r;            // = n*8 + b
            float* op = out + ((size_t)(row & 7) * N_NODES + (row >> 3)) * CH + c;
            float v = acc[ct][r];
            if (accum) v += __builtin_nontemporal_load(op);
            else       v += bv;
            __builtin_nontemporal_store(v, op);
        }
    }
}

extern "C" void kernel_launch(void* const* d_in, const int* in_sizes, int n_in,
                              void* d_out, int out_size, void* d_ws, size_t ws_size,
                              hipStream_t stream) {
    const float* x    = (const float*)d_in[0];   // [B,N,C]
    const int*   ei   = (const int*)d_in[1];     // [2,E]: row0=dst, row1=src
    const float* ew   = (const float*)d_in[2];   // [E]
    const float* W    = (const float*)d_in[3];   // [K,64,64]
    const float* bias = (const float*)d_in[4];   // [64]
    float* out = (float*)d_out;

    const int* dst = ei;
    const int* src = ei + N_EDGES;

    const size_t SB = TELEMS * sizeof(u16);      // 51.2 MB per t-buffer
    const size_t EXTRA = 2 * 200192 + (size_t)N_EDGES * sizeof(int2) + 49664;
    const size_t NEED_PRIMARY = 6 * SB + EXTRA;  // ~314.3 MB
    const bool primary = (ws_size >= NEED_PRIMARY);
    const int nbuf = primary ? 6 : 3;

    char* ws = (char*)d_ws;
    size_t off = 0;
    u16* tbase = (u16*)(ws + off); off += (size_t)nbuf * SB;   // t0(=x bf16), t1..
    int* row_ptr = (int*)(ws + off); off += 200192;
    int* cursor  = (int*)(ws + off); off += 200192;
    int2* edges  = (int2*)(ws + off); off += (size_t)N_EDGES * sizeof(int2);
    u16* wpack   = (u16*)(ws + off); off += 49664;
    (void)off; (void)n_in; (void)in_sizes; (void)out_size;

    // ---- CSR build + precompute (fused launches) ----
    (void)hipMemsetAsync(cursor, 0, (size_t)N_NODES * sizeof(int), stream);
    hist_cast_kernel<<<HIST_BLOCKS + CAST_BLOCKS, 256, 0, stream>>>(dst, cursor, x, tbase);
    scan_kernel<<<1, 1024, 0, stream>>>(cursor, row_ptr, N_NODES);
    scatter_pack_kernel<<<HIST_BLOCKS + PACK_BLOCKS, 256, 0, stream>>>(dst, src, ew, cursor,
                                                                       edges, W, wpack);

    const int SPMM_GRID = N_NODES / 4;           // 12500 blocks, 1 node per wave
    u16* t0 = tbase;
    if (primary) {
        u16* t1 = tbase + 1 * TELEMS;
        u16* t2 = tbase + 2 * TELEMS;
        u16* t3 = tbase + 3 * TELEMS;
        u16* t4 = tbase + 4 * TELEMS;
        u16* t5 = tbase + 5 * TELEMS;
        // chain A: batches 0-3 for all 5 steps (25.6 MB working set stays hot),
        // then chain B: batches 4-7. Halves are fully independent.
        for (int h = 0; h < 2; ++h) {
            spmm_kernel<false><<<SPMM_GRID, 256, 0, stream>>>(t0, nullptr, t1, row_ptr, edges, h);
            spmm_kernel<true ><<<SPMM_GRID, 256, 0, stream>>>(t1, t0, t2, row_ptr, edges, h);
            spmm_kernel<true ><<<SPMM_GRID, 256, 0, stream>>>(t2, t1, t3, row_ptr, edges, h);
            spmm_kernel<true ><<<SPMM_GRID, 256, 0, stream>>>(t3, t2, t4, row_ptr, edges, h);
            spmm_kernel<true ><<<SPMM_GRID, 256, 0, stream>>>(t4, t3, t5, row_ptr, edges, h);
        }
        out_gemm<<<NROWS / 16 / 4, 256, 0, stream>>>(tbase, TELEMS, wpack, bias, out, 6, 0);
    } else {
        // fallback: 3 rotating buffers + incremental GEMM accumulation
        u16* t1 = tbase + 1 * TELEMS;
        u16* t2 = tbase + 2 * TELEMS;
        const int GG = NROWS / 16 / 4;
        spmm_kernel<false><<<SPMM_GRID, 256, 0, stream>>>(t0, nullptr, t1, row_ptr, edges, 0);
        spmm_kernel<false><<<SPMM_GRID, 256, 0, stream>>>(t0, nullptr, t1, row_ptr, edges, 1);
        out_gemm<<<GG, 256, 0, stream>>>(t0, TELEMS, wpack, bias, out, 2, 0);          // bias + T0@W0 + T1@W1
        spmm_kernel<true ><<<SPMM_GRID, 256, 0, stream>>>(t1, t0, t2, row_ptr, edges, 0); // T2 -> t2
        spmm_kernel<true ><<<SPMM_GRID, 256, 0, stream>>>(t1, t0, t2, row_ptr, edges, 1);
        out_gemm<<<GG, 256, 0, stream>>>(t2, TELEMS, wpack + 2 * WSZ, bias, out, 1, 1);
        spmm_kernel<true ><<<SPMM_GRID, 256, 0, stream>>>(t2, t1, t0, row_ptr, edges, 0); // T3 -> t0
        spmm_kernel<true ><<<SPMM_GRID, 256, 0, stream>>>(t2, t1, t0, row_ptr, edges, 1);
        out_gemm<<<GG, 256, 0, stream>>>(t0, TELEMS, wpack + 3 * WSZ, bias, out, 1, 1);
        spmm_kernel<true ><<<SPMM_GRID, 256, 0, stream>>>(t0, t2, t1, row_ptr, edges, 0); // T4 -> t1
        spmm_kernel<true ><<<SPMM_GRID, 256, 0, stream>>>(t0, t2, t1, row_ptr, edges, 1);
        out_gemm<<<GG, 256, 0, stream>>>(t1, TELEMS, wpack + 4 * WSZ, bias, out, 1, 1);
        spmm_kernel<true ><<<SPMM_GRID, 256, 0, stream>>>(t1, t0, t2, row_ptr, edges, 0); // T5 -> t2
        spmm_kernel<true ><<<SPMM_GRID, 256, 0, stream>>>(t1, t0, t2, row_ptr, edges, 1);
        out_gemm<<<GG, 256, 0, stream>>>(t2, TELEMS, wpack + 5 * WSZ, bias, out, 1, 1);
    }
}

// Round 8
// 1015.781 us; speedup vs baseline: 1.0821x; 1.0033x over previous
//
#include <hip/hip_runtime.h>

#define N_NODES 50000
#define N_EDGES 800000
#define BATCH 8
#define CH 64
#define BC (BATCH * CH)                  // 512 elems per node row (node-major layout)
#define WSZ (CH * CH)
#define NROWS (BATCH * N_NODES)          // 400000 GEMM rows
#define TELEMS ((size_t)NROWS * CH)      // 25.6M elems per t-buffer
#define HIST_BLOCKS ((N_EDGES + 255) / 256)      // 3125
#define CAST_BLOCKS ((int)(TELEMS / 4 / 256))    // 25000
#define PACK_BLOCKS 12

typedef unsigned short u16;
typedef short bf16x8 __attribute__((ext_vector_type(8)));
typedef float f32x4 __attribute__((ext_vector_type(4)));
typedef unsigned short u16x4 __attribute__((ext_vector_type(4)));
typedef unsigned short u16x8 __attribute__((ext_vector_type(8)));

__device__ __forceinline__ u16 f2bf(float f) {          // RNE
    unsigned x = __float_as_uint(f);
    return (u16)((x + 0x7fffu + ((x >> 16) & 1u)) >> 16);
}
__device__ __forceinline__ float b2f(u16 u) {
    return __uint_as_float(((unsigned)u) << 16);
}

// ---------------- CSR build + input prep ----------------

// fused: blocks [0, HIST_BLOCKS) do the dst histogram; the rest transpose-cast
// x fp32 [B,N,C] -> bf16 [N,B,C]. Independent work, overlapped in one launch.
__global__ __launch_bounds__(256) void hist_cast_kernel(
        const int* __restrict__ dst, int* __restrict__ cursor,
        const float* __restrict__ x, u16* __restrict__ xb) {
    int bid = blockIdx.x;
    if (bid < HIST_BLOCKS) {
        int e = bid * 256 + threadIdx.x;
        if (e < N_EDGES) atomicAdd(&cursor[dst[e]], 1);
        return;
    }
    size_t i = (size_t)(bid - HIST_BLOCKS) * 256 + threadIdx.x;   // B*N*16 groups of 4ch
    f32x4 v = __builtin_nontemporal_load((const f32x4*)(x + i * 4));
    int c4 = (int)(i & 15);
    size_t bn = i >> 4;                                  // b*N + n
    int b = (int)(bn / N_NODES);
    int n = (int)(bn - (size_t)b * N_NODES);
    u16x4 o;
    o.x = f2bf(v.x); o.y = f2bf(v.y); o.z = f2bf(v.z); o.w = f2bf(v.w);
    *(u16x4*)(xb + ((size_t)n * BATCH + b) * CH + c4 * 4) = o;   // cached: gather source
}

__global__ void scan_kernel(int* cursor, int* __restrict__ row_ptr, int n) {
    const int T = 1024;
    int tid = threadIdx.x;
    int per = (n + T - 1) / T;
    int s = tid * per;
    int e = s + per; if (e > n) e = n;
    int sum = 0;
    for (int i = s; i < e; ++i) sum += cursor[i];
    __shared__ int lds[1024];
    lds[tid] = sum;
    __syncthreads();
    for (int off = 1; off < 1024; off <<= 1) {
        int t = (tid >= off) ? lds[tid - off] : 0;
        __syncthreads();
        lds[tid] += t;
        __syncthreads();
    }
    int run = lds[tid] - sum;
    for (int i = s; i < e; ++i) {
        int v = cursor[i];
        row_ptr[i] = run;
        cursor[i]  = run;
        run += v;
    }
    if (tid == T - 1) row_ptr[n] = run;
}

// fused: blocks [0, HIST_BLOCKS) scatter edges into CSR slots; the rest pack W
// into the MFMA B-fragment layout (frag id = (k*2+cct)*4+ct; lane holds
// B[k=quad*8+j][col=ct*16+(lane&15)]).
__global__ __launch_bounds__(256) void scatter_pack_kernel(
        const int* __restrict__ dst, const int* __restrict__ src,
        const float* __restrict__ w, int* cursor, int2* __restrict__ edges,
        const float* __restrict__ W, u16* __restrict__ wpack) {
    int bid = blockIdx.x;
    if (bid < HIST_BLOCKS) {
        int e = bid * 256 + threadIdx.x;
        if (e >= N_EDGES) return;
        int d = dst[e];
        int p = atomicAdd(&cursor[d], 1);
        edges[p] = make_int2(src[e], __float_as_int(w[e]));
        return;
    }
    int id = (bid - HIST_BLOCKS) * 256 + threadIdx.x;   // 48 frags * 64 lanes = 3072
    if (id >= 48 * 64) return;
    int lane = id & 63, frag = id >> 6;
    int ct = frag & 3, cct = (frag >> 2) & 1, k = frag >> 3;
    int m = lane & 15, quad = lane >> 4;
    int c = ct * 16 + m;
#pragma unroll
    for (int j = 0; j < 8; ++j) {
        int cc = cct * 32 + quad * 8 + j;
        wpack[(size_t)id * 8 + j] = f2bf(W[k * WSZ + cc * CH + c]);
    }
}

// ---------------- SPMM half-step: wave-per-node, batch-half, node-major ------
// Each SPMM is split into two half-passes over batches [0,4) / [4,8): gather
// working set 25.6 MB. Lane l covers batch half*4 + (l>>4), channels
// (l&15)*4..+4 (8B u16x4 load; wave = 512B contiguous half-row).
template <bool HAS_PREV>
__global__ __launch_bounds__(256) void spmm_kernel(
        const u16* __restrict__ tcur,
        const u16* __restrict__ tprev,
        u16* __restrict__ tnext,
        const int* __restrict__ row_ptr,
        const int2* __restrict__ edges,
        int half) {
    const int node = blockIdx.x * 4 + (threadIdx.x >> 6);
    const int lane = threadIdx.x & 63;
    const size_t lo = (size_t)half * 256 + (size_t)lane * 4;

    float acc[4];
#pragma unroll
    for (int q = 0; q < 4; ++q) acc[q] = 0.f;

    const int beg = row_ptr[node], end = row_ptr[node + 1];
    for (int e0 = beg; e0 < end; e0 += 64) {
        int m = end - e0; if (m > 64) m = 64;
        int2 ev = edges[e0 + (lane < m ? lane : 0)];
        int j = 0;
        for (; j + 4 <= m; j += 4) {                 // no predication, no waste
            int   s0 = __shfl(ev.x, j);
            int   s1 = __shfl(ev.x, j + 1);
            int   s2 = __shfl(ev.x, j + 2);
            int   s3 = __shfl(ev.x, j + 3);
            float w0 = __int_as_float(__shfl(ev.y, j));
            float w1 = __int_as_float(__shfl(ev.y, j + 1));
            float w2 = __int_as_float(__shfl(ev.y, j + 2));
            float w3 = __int_as_float(__shfl(ev.y, j + 3));
            u16x4 v0 = *(const u16x4*)(tcur + (size_t)s0 * BC + lo);
            u16x4 v1 = *(const u16x4*)(tcur + (size_t)s1 * BC + lo);
            u16x4 v2 = *(const u16x4*)(tcur + (size_t)s2 * BC + lo);
            u16x4 v3 = *(const u16x4*)(tcur + (size_t)s3 * BC + lo);
#pragma unroll
            for (int q = 0; q < 4; ++q) acc[q] = fmaf(w0, b2f(v0[q]), acc[q]);
#pragma unroll
            for (int q = 0; q < 4; ++q) acc[q] = fmaf(w1, b2f(v1[q]), acc[q]);
#pragma unroll
            for (int q = 0; q < 4; ++q) acc[q] = fmaf(w2, b2f(v2[q]), acc[q]);
#pragma unroll
            for (int q = 0; q < 4; ++q) acc[q] = fmaf(w3, b2f(v3[q]), acc[q]);
        }
        for (; j < m; ++j) {                         // wave-uniform tail, 0..3 edges
            int   s = __shfl(ev.x, j);
            float w = __int_as_float(__shfl(ev.y, j));
            u16x4 v = *(const u16x4*)(tcur + (size_t)s * BC + lo);
#pragma unroll
            for (int q = 0; q < 4; ++q) acc[q] = fmaf(w, b2f(v[q]), acc[q]);
        }
    }

    const size_t idx = (size_t)node * BC + lo;
    u16x4 o;
    if (HAS_PREV) {
        u16x4 pv = *(const u16x4*)(tprev + idx);
#pragma unroll
        for (int q = 0; q < 4; ++q) o[q] = f2bf(2.f * acc[q] - b2f(pv[q]));
    } else {
#pragma unroll
        for (int q = 0; q < 4; ++q) o[q] = f2bf(acc[q]);
    }
    *(u16x4*)(tnext + idx) = o;   // cached: next half-step's gather source
}

// ---------------- final GEMM: out = bias + sum_k t_k @ W_k (MFMA bf16) ----------------
// wave = one 16-row tile (rows are (n,b) pairs: r = n*8 + b), all 64 output cols.
// NK compile-time: fully unrolled, ALL A-fragment loads hoisted before the MFMA
// chain (12 loads in flight per wave instead of 1 -> no per-k vmcnt(0) stall).
// MFMA nesting (k, cct, ct) identical to previous version -> bit-identical C.
// C-store remaps to out[b][n][c]. ACCUM: out += ..., else out = bias + ...
template <int NK, bool ACCUM>
__global__ __launch_bounds__(256) void out_gemm(
        const u16* __restrict__ tbase, size_t tstride,
        const u16* __restrict__ wpack,      // already offset by k0*WSZ
        const float* __restrict__ bias,
        float* __restrict__ out) {
    const int wave = threadIdx.x >> 6, lane = threadIdx.x & 63;
    const int tile = blockIdx.x * 4 + wave;          // 25000 tiles
    const int row0 = tile * 16;
    const int m = lane & 15, quad = lane >> 4;

    bf16x8 A[NK][2];
#pragma unroll
    for (int k = 0; k < NK; ++k) {
        const u16* t = tbase + (size_t)k * tstride + (size_t)(row0 + m) * CH + quad * 8;
#pragma unroll
        for (int cct = 0; cct < 2; ++cct)
            A[k][cct] = *(const bf16x8*)(t + cct * 32);
    }

    f32x4 acc[4];
#pragma unroll
    for (int ct = 0; ct < 4; ++ct) acc[ct] = (f32x4){0.f, 0.f, 0.f, 0.f};

#pragma unroll
    for (int k = 0; k < NK; ++k) {
#pragma unroll
        for (int cct = 0; cct < 2; ++cct) {
#pragma unroll
            for (int ct = 0; ct < 4; ++ct) {
                bf16x8 B = *(const bf16x8*)(wpack + (size_t)(((k * 2 + cct) * 4 + ct) * 64 + lane) * 8);
                acc[ct] = __builtin_amdgcn_mfma_f32_16x16x32_bf16(A[k][cct], B, acc[ct], 0, 0, 0);
            }
        }
    }

#pragma unroll
    for (int ct = 0; ct < 4; ++ct) {
        const int c = ct * 16 + m;
        const float bv = bias[c];
#pragma unroll
        for (int r = 0; r < 4; ++r) {
            int row = row0 + quad * 4 + r;            // = n*8 + b
            float* op = out + ((size_t)(row & 7) * N_NODES + (row >> 3)) * CH + c;
            float v = acc[ct][r];
            if (ACCUM) v += __builtin_nontemporal_load(op);
            else       v += bv;
            __builtin_nontemporal_store(v, op);
        }
    }
}

extern "C" void kernel_launch(void* const* d_in, const int* in_sizes, int n_in,
                              void* d_out, int out_size, void* d_ws, size_t ws_size,
                              hipStream_t stream) {
    const float* x    = (const float*)d_in[0];   // [B,N,C]
    const int*   ei   = (const int*)d_in[1];     // [2,E]: row0=dst, row1=src
    const float* ew   = (const float*)d_in[2];   // [E]
    const float* W    = (const float*)d_in[3];   // [K,64,64]
    const float* bias = (const float*)d_in[4];   // [64]
    float* out = (float*)d_out;

    const int* dst = ei;
    const int* src = ei + N_EDGES;

    const size_t SB = TELEMS * sizeof(u16);      // 51.2 MB per t-buffer
    const size_t EXTRA = 2 * 200192 + (size_t)N_EDGES * sizeof(int2) + 49664;
    const size_t NEED_PRIMARY = 6 * SB + EXTRA;  // ~314.3 MB
    const bool primary = (ws_size >= NEED_PRIMARY);
    const int nbuf = primary ? 6 : 3;

    char* ws = (char*)d_ws;
    size_t off = 0;
    u16* tbase = (u16*)(ws + off); off += (size_t)nbuf * SB;   // t0(=x bf16), t1..
    int* row_ptr = (int*)(ws + off); off += 200192;
    int* cursor  = (int*)(ws + off); off += 200192;
    int2* edges  = (int2*)(ws + off); off += (size_t)N_EDGES * sizeof(int2);
    u16* wpack   = (u16*)(ws + off); off += 49664;
    (void)off; (void)n_in; (void)in_sizes; (void)out_size;

    // ---- CSR build + precompute (fused launches) ----
    (void)hipMemsetAsync(cursor, 0, (size_t)N_NODES * sizeof(int), stream);
    hist_cast_kernel<<<HIST_BLOCKS + CAST_BLOCKS, 256, 0, stream>>>(dst, cursor, x, tbase);
    scan_kernel<<<1, 1024, 0, stream>>>(cursor, row_ptr, N_NODES);
    scatter_pack_kernel<<<HIST_BLOCKS + PACK_BLOCKS, 256, 0, stream>>>(dst, src, ew, cursor,
                                                                       edges, W, wpack);

    const int SPMM_GRID = N_NODES / 4;           // 12500 blocks, 1 node per wave
    const int GG = NROWS / 16 / 4;               // out_gemm grid
    u16* t0 = tbase;
    if (primary) {
        u16* t1 = tbase + 1 * TELEMS;
        u16* t2 = tbase + 2 * TELEMS;
        u16* t3 = tbase + 3 * TELEMS;
        u16* t4 = tbase + 4 * TELEMS;
        u16* t5 = tbase + 5 * TELEMS;
        // chain A: batches 0-3 for all 5 steps (25.6 MB working set stays hot),
        // then chain B: batches 4-7. Halves are fully independent.
        for (int h = 0; h < 2; ++h) {
            spmm_kernel<false><<<SPMM_GRID, 256, 0, stream>>>(t0, nullptr, t1, row_ptr, edges, h);
            spmm_kernel<true ><<<SPMM_GRID, 256, 0, stream>>>(t1, t0, t2, row_ptr, edges, h);
            spmm_kernel<true ><<<SPMM_GRID, 256, 0, stream>>>(t2, t1, t3, row_ptr, edges, h);
            spmm_kernel<true ><<<SPMM_GRID, 256, 0, stream>>>(t3, t2, t4, row_ptr, edges, h);
            spmm_kernel<true ><<<SPMM_GRID, 256, 0, stream>>>(t4, t3, t5, row_ptr, edges, h);
        }
        out_gemm<6, false><<<GG, 256, 0, stream>>>(tbase, TELEMS, wpack, bias, out);
    } else {
        // fallback: 3 rotating buffers + incremental GEMM accumulation
        u16* t1 = tbase + 1 * TELEMS;
        u16* t2 = tbase + 2 * TELEMS;
        spmm_kernel<false><<<SPMM_GRID, 256, 0, stream>>>(t0, nullptr, t1, row_ptr, edges, 0);
        spmm_kernel<false><<<SPMM_GRID, 256, 0, stream>>>(t0, nullptr, t1, row_ptr, edges, 1);
        out_gemm<2, false><<<GG, 256, 0, stream>>>(t0, TELEMS, wpack, bias, out);          // bias + T0@W0 + T1@W1
        spmm_kernel<true ><<<SPMM_GRID, 256, 0, stream>>>(t1, t0, t2, row_ptr, edges, 0);  // T2 -> t2
        spmm_kernel<true ><<<SPMM_GRID, 256, 0, stream>>>(t1, t0, t2, row_ptr, edges, 1);
        out_gemm<1, true ><<<GG, 256, 0, stream>>>(t2, TELEMS, wpack + 2 * WSZ, bias, out);
        spmm_kernel<true ><<<SPMM_GRID, 256, 0, stream>>>(t2, t1, t0, row_ptr, edges, 0);  // T3 -> t0
        spmm_kernel<true ><<<SPMM_GRID, 256, 0, stream>>>(t2, t1, t0, row_ptr, edges, 1);
        out_gemm<1, true ><<<GG, 256, 0, stream>>>(t0, TELEMS, wpack + 3 * WSZ, bias, out);
        spmm_kernel<true ><<<SPMM_GRID, 256, 0, stream>>>(t0, t2, t1, row_ptr, edges, 0);  // T4 -> t1
        spmm_kernel<true ><<<SPMM_GRID, 256, 0, stream>>>(t0, t2, t1, row_ptr, edges, 1);
        out_gemm<1, true ><<<GG, 256, 0, stream>>>(t1, TELEMS, wpack + 4 * WSZ, bias, out);
        spmm_kernel<true ><<<SPMM_GRID, 256, 0, stream>>>(t1, t0, t2, row_ptr, edges, 0);  // T5 -> t2
        spmm_kernel<true ><<<SPMM_GRID, 256, 0, stream>>>(t1, t0, t2, row_ptr, edges, 1);
        out_gemm<1, true ><<<GG, 256, 0, stream>>>(t2, TELEMS, wpack + 5 * WSZ, bias, out);
    }
}